// Round 2
// baseline (2041.777 us; speedup 1.0000x reference)
//
#include <hip/hip_runtime.h>

typedef short s8v __attribute__((ext_vector_type(8)));
typedef float f4v __attribute__((ext_vector_type(4)));
typedef unsigned short u16;

// ---------------- sizes ----------------
// V=50000 D=300 H=256 T=34 B=64 S=256; M = S*B = 16384; K_in padded 300->320
constexpr int MB = 64, SS = 256, DD = 300, DP = 320, HH = 256, G4 = 1024, TT = 34, TP = 48;
constexpr int MM = MB * SS; // 16384, row m = s*64 + b

// workspace offsets (bytes)
constexpr size_t OFF_XBF  = 0;                                   // [16384][320] bf16
constexpr size_t OFF_WIH  = OFF_XBF  + (size_t)MM * DP * 2;      // [2048][320] bf16
constexpr size_t OFF_WHH  = OFF_WIH  + (size_t)2048 * DP * 2;    // [2][1024][256] bf16
constexpr size_t OFF_WOUT = OFF_WHH  + (size_t)2048 * HH * 2;    // [48][512] bf16
constexpr size_t OFF_XG   = OFF_WOUT + (size_t)TP * 512 * 2;     // [16384][2048] bf16
constexpr size_t OFF_HBUF = OFF_XG   + (size_t)MM * 2048 * 2;    // [2buf][2dir][64][256] bf16
constexpr size_t OFF_HID  = OFF_HBUF + (size_t)4 * 64 * 256 * 2; // [16384][512] bf16
constexpr size_t OFF_EM   = OFF_HID  + (size_t)MM * 512 * 2;     // [16384][36] f32
constexpr size_t OFF_LLH  = OFF_EM   + (size_t)MM * 36 * 4;      // [64] f32
constexpr size_t OFF_SYNC = OFF_LLH  + 256;                      // [2][256] int

__device__ inline u16 f2bf(float f) {
  unsigned u = __builtin_bit_cast(unsigned, f);
  unsigned r = u + 0x7fffu + ((u >> 16) & 1u);
  return (u16)(r >> 16);
}
__device__ inline float bf2f(u16 h) {
  return __builtin_bit_cast(float, (unsigned)h << 16);
}
__device__ inline float sigf(float x) { return __fdividef(1.f, 1.f + __expf(-x)); }
__device__ inline float tanhf_(float x) {
  float e = __expf(2.f * x);
  return __fdividef(e - 1.f, e + 1.f);
}
// coherent (write-through-to-coherent-point) 2B store: never dirty in L2,
// so a plain vmcnt(0) drain makes it agent-visible without buffer_wbl2.
__device__ inline void store_short_coh(u16* p, u16 v) {
  asm volatile("global_store_short %0, %1, off sc0 sc1" : : "v"(p), "v"((unsigned)v) : "memory");
}

// ---------------- K1: gather + bf16 conversions ----------------
constexpr int XBF_CH = MM * (DP / 8);       // 655360
constexpr int WIH_CH = 2048 * (DP / 8);     // 81920
constexpr int WHH_CH = 2048 * (HH / 8);     // 65536
constexpr int WOUT_CH = TP * (512 / 8);     // 3072
constexpr int TOT_CH = XBF_CH + WIH_CH + WHH_CH + WOUT_CH; // 805888

__global__ __launch_bounds__(256) void k_prep(
    const int* __restrict__ batch, const float* __restrict__ emb,
    const float* __restrict__ wihf, const float* __restrict__ wihb,
    const float* __restrict__ whhf, const float* __restrict__ whhb,
    const float* __restrict__ wout,
    u16* __restrict__ xbf, u16* __restrict__ wih,
    u16* __restrict__ whh, u16* __restrict__ wob) {
  int cid = blockIdx.x * 256 + threadIdx.x;
  if (cid >= TOT_CH) return;
  union { u16 u[8]; uint4 v; } pk;
  if (cid < XBF_CH) {
    int m = cid / 40, cc = cid - m * 40, d0 = cc * 8;
    int b = m & 63, s = m >> 6;
    int tok = batch[b * SS + s];
    const float* src = emb + (size_t)tok * DD;
    #pragma unroll
    for (int j = 0; j < 8; ++j) { int d = d0 + j; pk.u[j] = f2bf(d < DD ? src[d] : 0.f); }
    *(uint4*)(xbf + (size_t)m * DP + d0) = pk.v;
  } else if (cid < XBF_CH + WIH_CH) {
    int c2 = cid - XBF_CH;
    int row = c2 / 40, cc = c2 - row * 40, d0 = cc * 8;
    const float* src = row < 1024 ? (wihf + (size_t)row * DD) : (wihb + (size_t)(row - 1024) * DD);
    #pragma unroll
    for (int j = 0; j < 8; ++j) { int d = d0 + j; pk.u[j] = f2bf(d < DD ? src[d] : 0.f); }
    *(uint4*)(wih + (size_t)row * DP + d0) = pk.v;
  } else if (cid < XBF_CH + WIH_CH + WHH_CH) {
    int c2 = cid - (XBF_CH + WIH_CH);
    int row = c2 >> 5, d0 = (c2 & 31) * 8;
    const float* src = row < 1024 ? (whhf + (size_t)row * HH) : (whhb + (size_t)(row - 1024) * HH);
    #pragma unroll
    for (int j = 0; j < 8; ++j) pk.u[j] = f2bf(src[d0 + j]);
    *(uint4*)(whh + (size_t)row * HH + d0) = pk.v;
  } else {
    int c2 = cid - (XBF_CH + WIH_CH + WHH_CH);
    int row = c2 >> 6, d0 = (c2 & 63) * 8;
    #pragma unroll
    for (int j = 0; j < 8; ++j) pk.u[j] = f2bf(row < TT ? wout[(size_t)row * 512 + d0 + j] : 0.f);
    *(uint4*)(wob + (size_t)row * 512 + d0) = pk.v;
  }
}

// ---------------- K2: input-projection GEMM: xg[m][n] = xbf[m][k] . wih[n][k] + bias[n] ----------------
__global__ __launch_bounds__(256) void k_xg(
    const u16* __restrict__ xbf, const u16* __restrict__ wih,
    const float* __restrict__ bf_, const float* __restrict__ bb_,
    u16* __restrict__ xg) {
  __shared__ u16 As[128][40];
  __shared__ u16 Bs[128][40];
  int m0 = blockIdx.x * 128, n0 = blockIdx.y * 128;
  int tid = threadIdx.x, lane = tid & 63, wid = tid >> 6;
  int wr = wid >> 1, wc = wid & 1;
  int r_lo = lane & 15, kc = (lane >> 4) * 8, row_hi = (lane >> 4) * 4;
  f4v acc[4][4] = {};
  for (int kt = 0; kt < 10; ++kt) {
    int k0 = kt * 32;
    #pragma unroll
    for (int i = 0; i < 2; ++i) {
      int cid = tid + 256 * i;
      int row = cid >> 2, cc = cid & 3;
      *(uint4*)(&As[row][cc * 8]) = *(const uint4*)(xbf + (size_t)(m0 + row) * DP + k0 + cc * 8);
      *(uint4*)(&Bs[row][cc * 8]) = *(const uint4*)(wih + (size_t)(n0 + row) * DP + k0 + cc * 8);
    }
    __syncthreads();
    s8v af[4], bfr[4];
    #pragma unroll
    for (int mi = 0; mi < 4; ++mi) af[mi] = *(const s8v*)(&As[wr * 64 + mi * 16 + r_lo][kc]);
    #pragma unroll
    for (int ni = 0; ni < 4; ++ni) bfr[ni] = *(const s8v*)(&Bs[wc * 64 + ni * 16 + r_lo][kc]);
    #pragma unroll
    for (int mi = 0; mi < 4; ++mi)
      #pragma unroll
      for (int ni = 0; ni < 4; ++ni)
        acc[mi][ni] = __builtin_amdgcn_mfma_f32_16x16x32_bf16(af[mi], bfr[ni], acc[mi][ni], 0, 0, 0);
    __syncthreads();
  }
  #pragma unroll
  for (int mi = 0; mi < 4; ++mi)
    #pragma unroll
    for (int ni = 0; ni < 4; ++ni) {
      int n = n0 + wc * 64 + ni * 16 + r_lo;
      float bias = n < 1024 ? bf_[n] : bb_[n - 1024];
      #pragma unroll
      for (int r = 0; r < 4; ++r) {
        int m = m0 + wr * 64 + mi * 16 + row_hi + r;
        xg[(size_t)m * 2048 + n] = f2bf(acc[mi][ni][r] + bias);
      }
    }
}

// ---------------- K3: persistent bidirectional LSTM ----------------
// 16 wgs: dir = blk>>3, slice = blk&7 (32 h-units). Weights LDS-resident.
// Cross-wg h exchange via coherent (sc0 sc1) stores + relaxed agent atomics:
// NO acq/rel fences -> no buffer_wbl2/buffer_inv -> L2 stays warm for xg.
__global__ __launch_bounds__(256, 1) void k_lstm(
    const u16* __restrict__ xg, const u16* __restrict__ whh,
    u16* __restrict__ hbuf, u16* __restrict__ hidden, int* __restrict__ sync) {
  extern __shared__ char smem_raw[];
  u16* Wl = (u16*)smem_raw;          // [128][264]
  int dir = blockIdx.x >> 3, sl = blockIdx.x & 7, j0 = sl * 32;
  int tid = threadIdx.x, lane = tid & 63, wid = tid >> 6;
  int r_lo = lane & 15, kc = (lane >> 4) * 8, row_hi = (lane >> 4) * 4;
  int* flag = sync + dir * 256;
  // load weight slice: local row = gate*32 + jl  ->  whh[dir][gate*256 + j0 + jl][:]
  #pragma unroll
  for (int i = 0; i < 16; ++i) {
    int cid = tid + 256 * i;
    int row = cid >> 5, cc = cid & 31;
    int gate = row >> 5, jl = row & 31;
    *(uint4*)(Wl + row * 264 + cc * 8) =
        *(const uint4*)(whh + (size_t)(dir * 1024 + gate * 256 + j0 + jl) * HH + cc * 8);
  }
  __syncthreads();
  float cst[4][2] = {};
  for (int step = 0; step < 256; ++step) {
    int s = dir ? (255 - step) : step;
    int p = step & 1;
    const u16* hin = hbuf + (size_t)(p * 2 + dir) * 64 * 256;
    u16* hout = hbuf + (size_t)((p ^ 1) * 2 + dir) * 64 * 256;
    // --- prefetch this step's xg gate slice (normal cached loads, issued
    // before the poll so HBM latency hides under the wait) ---
    u16 xr[4][2][4];
    #pragma unroll
    for (int r = 0; r < 4; ++r) {
      int b = wid * 16 + row_hi + r;
      const u16* xb = xg + (size_t)(s * 64 + b) * 2048 + dir * 1024 + j0;
      #pragma unroll
      for (int jj = 0; jj < 2; ++jj)
        #pragma unroll
        for (int g = 0; g < 4; ++g)
          xr[r][jj][g] = xb[g * 256 + jj * 16 + r_lo];
    }
    asm volatile("" ::: "memory");  // pin prefetch above the poll
    // --- wait for all 8 slices of h_{step-1} ---
    if (step > 0) {
      const int* fl = flag + (step - 1);
      while (__hip_atomic_load(fl, __ATOMIC_RELAXED, __HIP_MEMORY_SCOPE_AGENT) < 8)
        __builtin_amdgcn_s_sleep(1);
    }
    // --- load h A-fragments straight from global (coherent, bypass stale L2) ---
    union { unsigned u[4]; s8v v; } hf[8];
    const unsigned* hrow = (const unsigned*)(hin + (wid * 16 + r_lo) * 256 + kc);
    #pragma unroll
    for (int kt = 0; kt < 8; ++kt) {
      #pragma unroll
      for (int q = 0; q < 4; ++q)
        hf[kt].u[q] = __hip_atomic_load(hrow + kt * 8 + q, __ATOMIC_RELAXED, __HIP_MEMORY_SCOPE_AGENT);
    }
    f4v acc[8] = {};
    #pragma unroll
    for (int kt = 0; kt < 8; ++kt) {
      #pragma unroll
      for (int nt = 0; nt < 8; ++nt) {
        s8v b = *(const s8v*)(Wl + (nt * 16 + r_lo) * 264 + kt * 32 + kc);
        acc[nt] = __builtin_amdgcn_mfma_f32_16x16x32_bf16(hf[kt].v, b, acc[nt], 0, 0, 0);
      }
    }
    // epilogue: lane owns b = wid*16 + row_hi + r, jl = jj*16 + r_lo
    #pragma unroll
    for (int r = 0; r < 4; ++r) {
      int b = wid * 16 + row_hi + r;
      #pragma unroll
      for (int jj = 0; jj < 2; ++jj) {
        int jl = jj * 16 + r_lo;
        float gi = acc[0 + jj][r] + bf2f(xr[r][jj][0]);
        float gf = acc[2 + jj][r] + bf2f(xr[r][jj][1]);
        float gg = acc[4 + jj][r] + bf2f(xr[r][jj][2]);
        float go = acc[6 + jj][r] + bf2f(xr[r][jj][3]);
        float cv = sigf(gf) * cst[r][jj] + sigf(gi) * tanhf_(gg);
        cst[r][jj] = cv;
        u16 hv = f2bf(sigf(go) * tanhf_(cv));
        store_short_coh(hout + b * 256 + j0 + jl, hv);
        hidden[(size_t)(s * 64 + b) * 512 + dir * 256 + j0 + jl] = hv;
      }
    }
    // drain write-through stores (they are at the coherent point once vmcnt
    // retires -> no cache flush needed), then publish.
    asm volatile("s_waitcnt vmcnt(0)" ::: "memory");
    __syncthreads();
    if (tid == 0)
      __hip_atomic_fetch_add(flag + step, 1, __ATOMIC_RELAXED, __HIP_MEMORY_SCOPE_AGENT);
  }
}

// ---------------- K4: emission GEMM: em[m][t] = hidden[m][k] . wout[t][k] + b_out[t] ----------------
__global__ __launch_bounds__(64) void k_emit(
    const u16* __restrict__ hidden, const u16* __restrict__ wob,
    const float* __restrict__ bout, float* __restrict__ em) {
  int m0 = blockIdx.x * 16;
  int lane = threadIdx.x;
  int r_lo = lane & 15, kc = (lane >> 4) * 8, row_hi = (lane >> 4) * 4;
  f4v acc[3] = {};
  #pragma unroll
  for (int kt = 0; kt < 16; ++kt) {
    int k0 = kt * 32 + kc;
    s8v a = *(const s8v*)(hidden + (size_t)(m0 + r_lo) * 512 + k0);
    #pragma unroll
    for (int nt = 0; nt < 3; ++nt) {
      s8v b = *(const s8v*)(wob + (size_t)(nt * 16 + r_lo) * 512 + k0);
      acc[nt] = __builtin_amdgcn_mfma_f32_16x16x32_bf16(a, b, acc[nt], 0, 0, 0);
    }
  }
  #pragma unroll
  for (int nt = 0; nt < 3; ++nt) {
    int t = nt * 16 + r_lo;
    if (t < TT) {
      float bo = bout[t];
      #pragma unroll
      for (int r = 0; r < 4; ++r)
        em[(size_t)(m0 + row_hi + r) * 36 + t] = acc[nt][r] + bo;
    }
  }
}

// ---------------- K5: CRF per-sequence NLL ----------------
__global__ __launch_bounds__(64) void k_crf(
    const float* __restrict__ em, const int* __restrict__ tags,
    const float* __restrict__ startt, const float* __restrict__ endt,
    const float* __restrict__ trans, float* __restrict__ llh) {
  __shared__ float tr[34][35];
  __shared__ float al[2][40];
  int b = blockIdx.x, l = threadIdx.x;
  for (int i = l; i < TT * TT; i += 64) tr[i / TT][i - (i / TT) * TT] = trans[i];
  const int* tg = tags + b * SS;
  float np = 0.f;
  for (int s = l; s < SS; s += 64) {
    int t = tg[s];
    np += em[(size_t)(s * 64 + b) * 36 + t];
    if (s < SS - 1) np += trans[t * TT + tg[s + 1]];
  }
  #pragma unroll
  for (int o = 32; o; o >>= 1) np += __shfl_down(np, o, 64);
  float num = 0.f;
  if (l == 0) num = np + startt[tg[0]] + endt[tg[SS - 1]];
  if (l < TT) al[0][l] = startt[l] + em[(size_t)(0 * 64 + b) * 36 + l];
  __syncthreads();
  for (int s = 1; s < SS; ++s) {
    int p = s & 1;
    if (l < TT) {
      float m = -1e30f;
      for (int t = 0; t < TT; ++t) m = fmaxf(m, al[p ^ 1][t] + tr[t][l]);
      float sum = 0.f;
      for (int t = 0; t < TT; ++t) sum += __expf(al[p ^ 1][t] + tr[t][l] - m);
      al[p][l] = m + __logf(sum) + em[(size_t)(s * 64 + b) * 36 + l];
    }
    __syncthreads();
  }
  if (l == 0) {
    int p = (SS - 1) & 1;
    float m = -1e30f;
    for (int t = 0; t < TT; ++t) m = fmaxf(m, al[p][t] + endt[t]);
    float sum = 0.f;
    for (int t = 0; t < TT; ++t) sum += __expf(al[p][t] + endt[t] - m);
    llh[b] = num - (m + __logf(sum));
  }
}

// ---------------- K6: final reduce ----------------
__global__ __launch_bounds__(64) void k_red(const float* __restrict__ llh, float* __restrict__ out) {
  float v = llh[threadIdx.x];
  #pragma unroll
  for (int o = 32; o; o >>= 1) v += __shfl_down(v, o, 64);
  if (threadIdx.x == 0) out[0] = -v * (1.f / 64.f);
}

extern "C" void kernel_launch(void* const* d_in, const int* in_sizes, int n_in,
                              void* d_out, int out_size, void* d_ws, size_t ws_size,
                              hipStream_t stream) {
  const int* batch = (const int*)d_in[0];
  const int* tags = (const int*)d_in[1];
  const float* emb = (const float*)d_in[3];
  const float* wihf = (const float*)d_in[4];
  const float* whhf = (const float*)d_in[5];
  const float* bf_ = (const float*)d_in[6];
  const float* wihb = (const float*)d_in[7];
  const float* whhb = (const float*)d_in[8];
  const float* bb_ = (const float*)d_in[9];
  const float* wout = (const float*)d_in[10];
  const float* bout = (const float*)d_in[11];
  const float* startt = (const float*)d_in[12];
  const float* endt = (const float*)d_in[13];
  const float* trans = (const float*)d_in[14];

  char* ws = (char*)d_ws;
  u16* xbf  = (u16*)(ws + OFF_XBF);
  u16* wih  = (u16*)(ws + OFF_WIH);
  u16* whh  = (u16*)(ws + OFF_WHH);
  u16* wob  = (u16*)(ws + OFF_WOUT);
  u16* xg   = (u16*)(ws + OFF_XG);
  u16* hbuf = (u16*)(ws + OFF_HBUF);
  u16* hid  = (u16*)(ws + OFF_HID);
  float* em = (float*)(ws + OFF_EM);
  float* llh = (float*)(ws + OFF_LLH);
  int* syncb = (int*)(ws + OFF_SYNC);
  float* out = (float*)d_out;

  hipFuncSetAttribute((const void*)k_lstm, hipFuncAttributeMaxDynamicSharedMemorySize, 128 * 264 * 2);

  hipMemsetAsync(hbuf, 0, 4 * 64 * 256 * 2, stream);
  hipMemsetAsync(syncb, 0, 2 * 256 * 4, stream);

  k_prep<<<TOT_CH / 256, 256, 0, stream>>>(batch, emb, wihf, wihb, whhf, whhb, wout,
                                           xbf, wih, whh, wob);
  k_xg<<<dim3(MM / 128, 2048 / 128), 256, 0, stream>>>(xbf, wih, bf_, bb_, xg);
  k_lstm<<<16, 256, 128 * 264 * 2, stream>>>(xg, whh, hbuf, hid, syncb);
  k_emit<<<MM / 16, 64, 0, stream>>>(hid, wob, bout, em);
  k_crf<<<64, 64, 0, stream>>>(em, tags, startt, endt, trans, llh);
  k_red<<<1, 64, 0, stream>>>(llh, out);
}

// Round 4
// 1537.597 us; speedup vs baseline: 1.3279x; 1.3279x over previous
//
#include <hip/hip_runtime.h>

typedef short s8v __attribute__((ext_vector_type(8)));
typedef float f4v __attribute__((ext_vector_type(4)));
typedef unsigned short u16;
typedef unsigned char u8;
typedef long ll;  // 64-bit on amdgcn

// ---------------- sizes ----------------
// V=50000 D=300 H=256 T=34 B=64 S=256; M = S*B = 16384; K_in padded 300->320
constexpr int MB = 64, SS = 256, DD = 300, DP = 320, HH = 256, TT = 34, TP = 48;
constexpr int MM = MB * SS;

// workspace offsets (bytes) — total ~98.6 MB (round-1/2 used 99.3 MB, so safe)
constexpr size_t OFF_XBF  = 0;                                    // [16384][320] bf16
constexpr size_t OFF_WIH  = OFF_XBF  + (size_t)MM * DP * 2;       // [2048][320] bf16
constexpr size_t OFF_WHH8 = OFF_WIH  + (size_t)2048 * DP * 2;     // [2][1024][256] fp8 e4m3
constexpr size_t OFF_WOUT = OFF_WHH8 + (size_t)2048 * HH;         // [48][512] bf16
constexpr size_t OFF_XG   = OFF_WOUT + (size_t)TP * 512 * 2;      // [2dir][4bg][256s][1024n][16b] bf16
constexpr size_t OFF_HID  = OFF_XG   + (size_t)2 * 4 * 256 * 1024 * 16 * 2; // [16384][512] bf16
constexpr size_t OFF_EM   = OFF_HID  + (size_t)MM * 512 * 2;      // [16384][36] f32
constexpr size_t OFF_LLH  = OFF_EM   + (size_t)MM * 36 * 4;       // [64] f32

__device__ inline u16 f2bf(float f) {
  unsigned u = __builtin_bit_cast(unsigned, f);
  unsigned r = u + 0x7fffu + ((u >> 16) & 1u);
  return (u16)(r >> 16);
}
__device__ inline float bf2f(u16 h) {
  return __builtin_bit_cast(float, (unsigned)h << 16);
}
__device__ inline float sigf(float x) { return __fdividef(1.f, 1.f + __expf(-x)); }
__device__ inline float tanhf_(float x) {
  float e = __expf(2.f * x);
  return __fdividef(e - 1.f, e + 1.f);
}
// f32 -> fp8 e4m3 (OCP, RNE + sat via HW convert)
__device__ inline u8 f2fp8(float f) {
  unsigned v;
  asm("v_cvt_pk_fp8_f32 %0, %1, %2" : "=v"(v) : "v"(f), "v"(f));
  return (u8)(v & 0xff);
}

// ---------------- K1: gather + conversions ----------------
constexpr int XBF_CH = MM * (DP / 8);       // 655360
constexpr int WIH_CH = 2048 * (DP / 8);     // 81920
constexpr int WHH_CH = 2048 * (HH / 8);     // 65536 (-> fp8 bytes)
constexpr int WOUT_CH = TP * (512 / 8);     // 3072
constexpr int TOT_CH = XBF_CH + WIH_CH + WHH_CH + WOUT_CH;

__global__ __launch_bounds__(256) void k_prep(
    const int* __restrict__ batch, const float* __restrict__ emb,
    const float* __restrict__ wihf, const float* __restrict__ wihb,
    const float* __restrict__ whhf, const float* __restrict__ whhb,
    const float* __restrict__ wout,
    u16* __restrict__ xbf, u16* __restrict__ wih,
    u8* __restrict__ whh8, u16* __restrict__ wob) {
  int cid = blockIdx.x * 256 + threadIdx.x;
  if (cid >= TOT_CH) return;
  union { u16 u[8]; uint4 v; } pk;
  if (cid < XBF_CH) {
    int m = cid / 40, cc = cid - m * 40, d0 = cc * 8;
    int b = m & 63, s = m >> 6;
    int tok = batch[b * SS + s];
    const float* src = emb + (size_t)tok * DD;
    #pragma unroll
    for (int j = 0; j < 8; ++j) { int d = d0 + j; pk.u[j] = f2bf(d < DD ? src[d] : 0.f); }
    *(uint4*)(xbf + (size_t)m * DP + d0) = pk.v;
  } else if (cid < XBF_CH + WIH_CH) {
    int c2 = cid - XBF_CH;
    int row = c2 / 40, cc = c2 - row * 40, d0 = cc * 8;
    const float* src = row < 1024 ? (wihf + (size_t)row * DD) : (wihb + (size_t)(row - 1024) * DD);
    #pragma unroll
    for (int j = 0; j < 8; ++j) { int d = d0 + j; pk.u[j] = f2bf(d < DD ? src[d] : 0.f); }
    *(uint4*)(wih + (size_t)row * DP + d0) = pk.v;
  } else if (cid < XBF_CH + WIH_CH + WHH_CH) {
    int c2 = cid - (XBF_CH + WIH_CH);
    int row = c2 >> 5, d0 = (c2 & 31) * 8;
    const float* src = (row < 1024 ? whhf + (size_t)row * HH : whhb + (size_t)(row - 1024) * HH) + d0;
    unsigned q0, q1, q2, q3;
    asm("v_cvt_pk_fp8_f32 %0, %1, %2" : "=v"(q0) : "v"(src[0]), "v"(src[1]));
    asm("v_cvt_pk_fp8_f32 %0, %1, %2" : "=v"(q1) : "v"(src[2]), "v"(src[3]));
    asm("v_cvt_pk_fp8_f32 %0, %1, %2" : "=v"(q2) : "v"(src[4]), "v"(src[5]));
    asm("v_cvt_pk_fp8_f32 %0, %1, %2" : "=v"(q3) : "v"(src[6]), "v"(src[7]));
    uint2 o;
    o.x = (q0 & 0xffffu) | (q1 << 16);
    o.y = (q2 & 0xffffu) | (q3 << 16);
    *(uint2*)(whh8 + (size_t)row * HH + d0) = o;
  } else {
    int c2 = cid - (XBF_CH + WIH_CH + WHH_CH);
    int row = c2 >> 6, d0 = (c2 & 63) * 8;
    #pragma unroll
    for (int j = 0; j < 8; ++j) pk.u[j] = f2bf(row < TT ? wout[(size_t)row * 512 + d0 + j] : 0.f);
    *(uint4*)(wob + (size_t)row * 512 + d0) = pk.v;
  }
}

// ---------------- K2: input GEMM: xgt[dir][bg][s][n][b16] = xbf[m][k].wih[n][k] + bias ----------------
__global__ __launch_bounds__(256) void k_xg(
    const u16* __restrict__ xbf, const u16* __restrict__ wih,
    const float* __restrict__ bf_, const float* __restrict__ bb_,
    u16* __restrict__ xgt) {
  __shared__ u16 As[128][40];
  __shared__ u16 Bs[128][40];
  int m0 = blockIdx.x * 128, n0 = blockIdx.y * 128;
  int tid = threadIdx.x, lane = tid & 63, wid = tid >> 6;
  int wr = wid >> 1, wc = wid & 1;
  int r_lo = lane & 15, kc = (lane >> 4) * 8, row_hi = (lane >> 4) * 4;
  f4v acc[4][4] = {};
  for (int kt = 0; kt < 10; ++kt) {
    int k0 = kt * 32;
    #pragma unroll
    for (int i = 0; i < 2; ++i) {
      int cid = tid + 256 * i;
      int row = cid >> 2, cc = cid & 3;
      *(uint4*)(&As[row][cc * 8]) = *(const uint4*)(xbf + (size_t)(m0 + row) * DP + k0 + cc * 8);
      *(uint4*)(&Bs[row][cc * 8]) = *(const uint4*)(wih + (size_t)(n0 + row) * DP + k0 + cc * 8);
    }
    __syncthreads();
    s8v af[4], bfr[4];
    #pragma unroll
    for (int mi = 0; mi < 4; ++mi) af[mi] = *(const s8v*)(&As[wr * 64 + mi * 16 + r_lo][kc]);
    #pragma unroll
    for (int ni = 0; ni < 4; ++ni) bfr[ni] = *(const s8v*)(&Bs[wc * 64 + ni * 16 + r_lo][kc]);
    #pragma unroll
    for (int mi = 0; mi < 4; ++mi)
      #pragma unroll
      for (int ni = 0; ni < 4; ++ni)
        acc[mi][ni] = __builtin_amdgcn_mfma_f32_16x16x32_bf16(af[mi], bfr[ni], acc[mi][ni], 0, 0, 0);
    __syncthreads();
  }
  #pragma unroll
  for (int mi = 0; mi < 4; ++mi)
    #pragma unroll
    for (int ni = 0; ni < 4; ++ni) {
      int n2 = n0 + wc * 64 + ni * 16 + r_lo;
      float bias = n2 < 1024 ? bf_[n2] : bb_[n2 - 1024];
      int dir = n2 >> 10, n = n2 & 1023;
      #pragma unroll
      for (int r = 0; r < 4; ++r) {
        int m = m0 + wr * 64 + mi * 16 + row_hi + r;
        int s = m >> 6, b = m & 63;
        xgt[((((size_t)dir * 4 + (b >> 4)) * 256 + s) * 1024 + n) * 16 + (b & 15)] =
            f2bf(acc[mi][ni][r] + bias);
      }
    }
}

// ---------------- K3: LSTM, zero inter-workgroup communication ----------------
// 8 wgs = 2 dir x 4 batch-groups(16). Each wg runs its whole 256-step chain on
// one CU: W_hh fp8 entirely in VGPRs (256/lane), h fp8 ping-pong in LDS (XOR-
// swizzled), xg gate slice prefetched one step ahead straight into MFMA C-in.
__global__ __launch_bounds__(256, 1) void k_lstm(
    const u16* __restrict__ xgt, const u8* __restrict__ whh8,
    u16* __restrict__ hidden) {
  __shared__ u8 hs[2][16 * 256];
  int wg = blockIdx.x, dir = wg >> 2, bg = wg & 3;
  int tid = threadIdx.x, lane = tid & 63, w = tid >> 6;
  int r_lo = lane & 15, hi = lane >> 4;

  // W fragments: wave w owns units [w*64, w*64+64) for all 4 gates.
  // nt = gate*4+ut -> rows gate*256 + w*64 + ut*16 + (lane&15), k-chunk hi*8.
  ll wf[16][8];
  const u8* wb = whh8 + (size_t)dir * 1024 * 256;
  #pragma unroll
  for (int g = 0; g < 4; ++g)
    #pragma unroll
    for (int ut = 0; ut < 4; ++ut) {
      const u8* rp = wb + (size_t)(g * 256 + w * 64 + ut * 16 + r_lo) * 256 + hi * 8;
      #pragma unroll
      for (int kt = 0; kt < 8; ++kt)
        wf[g * 4 + ut][kt] = *(const ll*)(rp + kt * 32);
    }
  for (int i = tid; i < 2 * 16 * 256 / 4; i += 256) ((int*)hs)[i] = 0;
  float c[16];
  #pragma unroll
  for (int i = 0; i < 16; ++i) c[i] = 0.f;

  const u16* xbase = xgt + (((size_t)(dir * 4 + bg) * 256) * 1024 + w * 64) * 16;
  ll xb[16];
  {
    int s0 = dir ? 255 : 0;
    #pragma unroll
    for (int g = 0; g < 4; ++g)
      #pragma unroll
      for (int ut = 0; ut < 4; ++ut)
        xb[g * 4 + ut] = *(const ll*)(xbase + ((size_t)s0 * 1024 + g * 256 + ut * 16 + r_lo) * 16 + hi * 4);
  }
  __syncthreads();

  u16* hidb = hidden + (size_t)(bg * 16) * 512 + dir * 256 + w * 64;
  for (int step = 0; step < 256; ++step) {
    int s = dir ? 255 - step : step;
    // acc starts at xg (bias + input projection already folded in)
    f4v acc[16];
    #pragma unroll
    for (int nt = 0; nt < 16; ++nt) {
      unsigned lo = (unsigned)(unsigned long)xb[nt];
      unsigned h32 = (unsigned)(((unsigned long)xb[nt]) >> 32);
      acc[nt][0] = bf2f((u16)(lo & 0xffff));
      acc[nt][1] = bf2f((u16)(lo >> 16));
      acc[nt][2] = bf2f((u16)(h32 & 0xffff));
      acc[nt][3] = bf2f((u16)(h32 >> 16));
    }
    // prefetch next step's xg (latency hidden under MFMA+epilogue)
    if (step < 255) {
      int sn = dir ? 254 - step : step + 1;
      #pragma unroll
      for (int g = 0; g < 4; ++g)
        #pragma unroll
        for (int ut = 0; ut < 4; ++ut)
          xb[g * 4 + ut] = *(const ll*)(xbase + ((size_t)sn * 1024 + g * 256 + ut * 16 + r_lo) * 16 + hi * 4);
    }
    // A-fragments: h[b=lane&15][k], XOR-swizzled chunks (conflict-free-ish)
    const u8* hp = hs[step & 1];
    ll av[8];
    #pragma unroll
    for (int kt = 0; kt < 8; ++kt)
      av[kt] = *(const ll*)(hp + r_lo * 256 + ((kt * 32 + hi * 8) ^ (r_lo << 3)));
    #pragma unroll
    for (int kt = 0; kt < 8; ++kt)
      #pragma unroll
      for (int nt = 0; nt < 16; ++nt)
        acc[nt] = __builtin_amdgcn_mfma_f32_16x16x32_fp8_fp8(av[kt], wf[nt][kt], acc[nt], 0, 0, 0);
    // epilogue: lane owns (b = hi*4+q, u = w*64 + ut*16 + r_lo)
    u8* hq = hs[(step + 1) & 1];
    u16* hrow = hidb + (size_t)s * 64 * 512;
    #pragma unroll
    for (int q = 0; q < 4; ++q) {
      int b = hi * 4 + q;
      #pragma unroll
      for (int ut = 0; ut < 4; ++ut) {
        float gi = acc[0 + ut][q], gf = acc[4 + ut][q];
        float gg = acc[8 + ut][q], go = acc[12 + ut][q];
        float cv = sigf(gf) * c[q * 4 + ut] + sigf(gi) * tanhf_(gg);
        c[q * 4 + ut] = cv;
        float hv = sigf(go) * tanhf_(cv);
        hq[b * 256 + ((w * 64 + ut * 16 + r_lo) ^ (b << 3))] = f2fp8(hv);
        hrow[(size_t)b * 512 + ut * 16 + r_lo] = f2bf(hv);
      }
    }
    __syncthreads();
  }
}

// ---------------- K4: emission GEMM ----------------
__global__ __launch_bounds__(64) void k_emit(
    const u16* __restrict__ hidden, const u16* __restrict__ wob,
    const float* __restrict__ bout, float* __restrict__ em) {
  int m0 = blockIdx.x * 16;
  int lane = threadIdx.x;
  int r_lo = lane & 15, kc = (lane >> 4) * 8, row_hi = (lane >> 4) * 4;
  f4v acc[3] = {};
  #pragma unroll
  for (int kt = 0; kt < 16; ++kt) {
    int k0 = kt * 32 + kc;
    s8v a = *(const s8v*)(hidden + (size_t)(m0 + r_lo) * 512 + k0);
    #pragma unroll
    for (int nt = 0; nt < 3; ++nt) {
      s8v b = *(const s8v*)(wob + (size_t)(nt * 16 + r_lo) * 512 + k0);
      acc[nt] = __builtin_amdgcn_mfma_f32_16x16x32_bf16(a, b, acc[nt], 0, 0, 0);
    }
  }
  #pragma unroll
  for (int nt = 0; nt < 3; ++nt) {
    int t = nt * 16 + r_lo;
    if (t < TT) {
      float bo = bout[t];
      #pragma unroll
      for (int r = 0; r < 4; ++r)
        em[(size_t)(m0 + row_hi + r) * 36 + t] = acc[nt][r] + bo;
    }
  }
}

// ---------------- K5: CRF per-sequence NLL ----------------
__global__ __launch_bounds__(64) void k_crf(
    const float* __restrict__ em, const int* __restrict__ tags,
    const float* __restrict__ startt, const float* __restrict__ endt,
    const float* __restrict__ trans, float* __restrict__ llh) {
  __shared__ float tr[34][35];
  __shared__ float al[2][40];
  int b = blockIdx.x, l = threadIdx.x;
  for (int i = l; i < TT * TT; i += 64) tr[i / TT][i - (i / TT) * TT] = trans[i];
  const int* tg = tags + b * SS;
  float np = 0.f;
  for (int s = l; s < SS; s += 64) {
    int t = tg[s];
    np += em[(size_t)(s * 64 + b) * 36 + t];
    if (s < SS - 1) np += trans[t * TT + tg[s + 1]];
  }
  #pragma unroll
  for (int o = 32; o; o >>= 1) np += __shfl_down(np, o, 64);
  float num = 0.f;
  if (l == 0) num = np + startt[tg[0]] + endt[tg[SS - 1]];
  if (l < TT) al[0][l] = startt[l] + em[(size_t)(0 * 64 + b) * 36 + l];
  __syncthreads();
  for (int s = 1; s < SS; ++s) {
    int p = s & 1;
    if (l < TT) {
      float m = -1e30f;
      for (int t = 0; t < TT; ++t) m = fmaxf(m, al[p ^ 1][t] + tr[t][l]);
      float sum = 0.f;
      for (int t = 0; t < TT; ++t) sum += __expf(al[p ^ 1][t] + tr[t][l] - m);
      al[p][l] = m + __logf(sum) + em[(size_t)(s * 64 + b) * 36 + l];
    }
    __syncthreads();
  }
  if (l == 0) {
    int p = (SS - 1) & 1;
    float m = -1e30f;
    for (int t = 0; t < TT; ++t) m = fmaxf(m, al[p][t] + endt[t]);
    float sum = 0.f;
    for (int t = 0; t < TT; ++t) sum += __expf(al[p][t] + endt[t] - m);
    llh[b] = num - (m + __logf(sum));
  }
}

// ---------------- K6: final reduce ----------------
__global__ __launch_bounds__(64) void k_red(const float* __restrict__ llh, float* __restrict__ out) {
  float v = llh[threadIdx.x];
  #pragma unroll
  for (int o = 32; o; o >>= 1) v += __shfl_down(v, o, 64);
  if (threadIdx.x == 0) out[0] = -v * (1.f / 64.f);
}

extern "C" void kernel_launch(void* const* d_in, const int* in_sizes, int n_in,
                              void* d_out, int out_size, void* d_ws, size_t ws_size,
                              hipStream_t stream) {
  const int* batch = (const int*)d_in[0];
  const int* tags = (const int*)d_in[1];
  const float* emb = (const float*)d_in[3];
  const float* wihf = (const float*)d_in[4];
  const float* whhf = (const float*)d_in[5];
  const float* bf_ = (const float*)d_in[6];
  const float* wihb = (const float*)d_in[7];
  const float* whhb = (const float*)d_in[8];
  const float* bb_ = (const float*)d_in[9];
  const float* wout = (const float*)d_in[10];
  const float* bout = (const float*)d_in[11];
  const float* startt = (const float*)d_in[12];
  const float* endt = (const float*)d_in[13];
  const float* trans = (const float*)d_in[14];

  char* ws = (char*)d_ws;
  u16* xbf  = (u16*)(ws + OFF_XBF);
  u16* wih  = (u16*)(ws + OFF_WIH);
  u8*  whh8 = (u8*)(ws + OFF_WHH8);
  u16* wob  = (u16*)(ws + OFF_WOUT);
  u16* xgt  = (u16*)(ws + OFF_XG);
  u16* hid  = (u16*)(ws + OFF_HID);
  float* em = (float*)(ws + OFF_EM);
  float* llh = (float*)(ws + OFF_LLH);
  float* out = (float*)d_out;

  k_prep<<<(TOT_CH + 255) / 256, 256, 0, stream>>>(batch, emb, wihf, wihb, whhf, whhb, wout,
                                                   xbf, wih, whh8, wob);
  k_xg<<<dim3(MM / 128, 2048 / 128), 256, 0, stream>>>(xbf, wih, bf_, bb_, xgt);
  k_lstm<<<8, 256, 0, stream>>>(xgt, whh8, hid);
  k_emit<<<MM / 16, 64, 0, stream>>>(hid, wob, bout, em);
  k_crf<<<64, 64, 0, stream>>>(em, tags, startt, endt, trans, llh);
  k_red<<<1, 64, 0, stream>>>(llh, out);
}

// Round 6
// 1373.200 us; speedup vs baseline: 1.4869x; 1.1197x over previous
//
#include <hip/hip_runtime.h>

typedef short s8v __attribute__((ext_vector_type(8)));
typedef float f4v __attribute__((ext_vector_type(4)));
typedef unsigned short u16;
typedef unsigned char u8;
typedef long ll;  // 64-bit on amdgcn

// ---------------- sizes ----------------
// V=50000 D=300 H=256 T=34 B=64 S=256; M = S*B = 16384; K_in padded 300->320
constexpr int MB = 64, SS = 256, DD = 300, DP = 320, HH = 256, TT = 34, TP = 48;
constexpr int MM = MB * SS;

// workspace offsets (bytes) — total ~98.6 MB
constexpr size_t OFF_XBF  = 0;                                    // [16384][320] bf16
constexpr size_t OFF_WIH  = OFF_XBF  + (size_t)MM * DP * 2;       // [2048][320] bf16
constexpr size_t OFF_WHH8 = OFF_WIH  + (size_t)2048 * DP * 2;     // [2][1024][256] fp8 e4m3
constexpr size_t OFF_WOUT = OFF_WHH8 + (size_t)2048 * HH;         // [48][512] bf16
constexpr size_t OFF_XG   = OFF_WOUT + (size_t)TP * 512 * 2;      // [2dir][4bg][256s][1024n][16b] bf16
constexpr size_t OFF_HID  = OFF_XG   + (size_t)2 * 4 * 256 * 1024 * 16 * 2; // [16384][512] bf16
constexpr size_t OFF_EM   = OFF_HID  + (size_t)MM * 512 * 2;      // [16384][36] f32
constexpr size_t OFF_LLH  = OFF_EM   + (size_t)MM * 36 * 4;      // [64] f32

__device__ inline u16 f2bf(float f) {
  unsigned u = __builtin_bit_cast(unsigned, f);
  unsigned r = u + 0x7fffu + ((u >> 16) & 1u);
  return (u16)(r >> 16);
}
__device__ inline float bf2f(u16 h) {
  return __builtin_bit_cast(float, (unsigned)h << 16);
}
__device__ inline float sigf(float x) { return __fdividef(1.f, 1.f + __expf(-x)); }
__device__ inline float tanhf_(float x) {
  float e = __expf(2.f * x);
  return __fdividef(e - 1.f, e + 1.f);
}
// f32 -> fp8 e4m3 (OCP, RNE + sat via HW convert)
__device__ inline u8 f2fp8(float f) {
  unsigned v;
  asm("v_cvt_pk_fp8_f32 %0, %1, %2" : "=v"(v) : "v"(f), "v"(f));
  return (u8)(v & 0xff);
}

// ---------------- K1: gather + conversions ----------------
constexpr int XBF_CH = MM * (DP / 8);       // 655360
constexpr int WIH_CH = 2048 * (DP / 8);     // 81920
constexpr int WHH_CH = 2048 * (HH / 8);     // 65536 (-> fp8 bytes)
constexpr int WOUT_CH = TP * (512 / 8);     // 3072
constexpr int TOT_CH = XBF_CH + WIH_CH + WHH_CH + WOUT_CH;

__global__ __launch_bounds__(256) void k_prep(
    const int* __restrict__ batch, const float* __restrict__ emb,
    const float* __restrict__ wihf, const float* __restrict__ wihb,
    const float* __restrict__ whhf, const float* __restrict__ whhb,
    const float* __restrict__ wout,
    u16* __restrict__ xbf, u16* __restrict__ wih,
    u8* __restrict__ whh8, u16* __restrict__ wob) {
  int cid = blockIdx.x * 256 + threadIdx.x;
  if (cid >= TOT_CH) return;
  union { u16 u[8]; uint4 v; } pk;
  if (cid < XBF_CH) {
    int m = cid / 40, cc = cid - m * 40, d0 = cc * 8;
    int b = m & 63, s = m >> 6;
    int tok = batch[b * SS + s];
    const float* src = emb + (size_t)tok * DD;
    #pragma unroll
    for (int j = 0; j < 8; ++j) { int d = d0 + j; pk.u[j] = f2bf(d < DD ? src[d] : 0.f); }
    *(uint4*)(xbf + (size_t)m * DP + d0) = pk.v;
  } else if (cid < XBF_CH + WIH_CH) {
    int c2 = cid - XBF_CH;
    int row = c2 / 40, cc = c2 - row * 40, d0 = cc * 8;
    const float* src = row < 1024 ? (wihf + (size_t)row * DD) : (wihb + (size_t)(row - 1024) * DD);
    #pragma unroll
    for (int j = 0; j < 8; ++j) { int d = d0 + j; pk.u[j] = f2bf(d < DD ? src[d] : 0.f); }
    *(uint4*)(wih + (size_t)row * DP + d0) = pk.v;
  } else if (cid < XBF_CH + WIH_CH + WHH_CH) {
    int c2 = cid - (XBF_CH + WIH_CH);
    int row = c2 >> 5, d0 = (c2 & 31) * 8;
    const float* src = (row < 1024 ? whhf + (size_t)row * HH : whhb + (size_t)(row - 1024) * HH) + d0;
    unsigned q0, q1, q2, q3;
    asm("v_cvt_pk_fp8_f32 %0, %1, %2" : "=v"(q0) : "v"(src[0]), "v"(src[1]));
    asm("v_cvt_pk_fp8_f32 %0, %1, %2" : "=v"(q1) : "v"(src[2]), "v"(src[3]));
    asm("v_cvt_pk_fp8_f32 %0, %1, %2" : "=v"(q2) : "v"(src[4]), "v"(src[5]));
    asm("v_cvt_pk_fp8_f32 %0, %1, %2" : "=v"(q3) : "v"(src[6]), "v"(src[7]));
    uint2 o;
    o.x = (q0 & 0xffffu) | (q1 << 16);
    o.y = (q2 & 0xffffu) | (q3 << 16);
    *(uint2*)(whh8 + (size_t)row * HH + d0) = o;
  } else {
    int c2 = cid - (XBF_CH + WIH_CH + WHH_CH);
    int row = c2 >> 6, d0 = (c2 & 63) * 8;
    #pragma unroll
    for (int j = 0; j < 8; ++j) pk.u[j] = f2bf(row < TT ? wout[(size_t)row * 512 + d0 + j] : 0.f);
    *(uint4*)(wob + (size_t)row * 512 + d0) = pk.v;
  }
}

// ---------------- K2: input GEMM: xgt[dir][bg][s][n][b16] = xbf[m][k].wih[n][k] + bias ----------------
__global__ __launch_bounds__(256) void k_xg(
    const u16* __restrict__ xbf, const u16* __restrict__ wih,
    const float* __restrict__ bf_, const float* __restrict__ bb_,
    u16* __restrict__ xgt) {
  __shared__ u16 As[128][40];
  __shared__ u16 Bs[128][40];
  int m0 = blockIdx.x * 128, n0 = blockIdx.y * 128;
  int tid = threadIdx.x, lane = tid & 63, wid = tid >> 6;
  int wr = wid >> 1, wc = wid & 1;
  int r_lo = lane & 15, kc = (lane >> 4) * 8, row_hi = (lane >> 4) * 4;
  f4v acc[4][4] = {};
  for (int kt = 0; kt < 10; ++kt) {
    int k0 = kt * 32;
    #pragma unroll
    for (int i = 0; i < 2; ++i) {
      int cid = tid + 256 * i;
      int row = cid >> 2, cc = cid & 3;
      *(uint4*)(&As[row][cc * 8]) = *(const uint4*)(xbf + (size_t)(m0 + row) * DP + k0 + cc * 8);
      *(uint4*)(&Bs[row][cc * 8]) = *(const uint4*)(wih + (size_t)(n0 + row) * DP + k0 + cc * 8);
    }
    __syncthreads();
    s8v af[4], bfr[4];
    #pragma unroll
    for (int mi = 0; mi < 4; ++mi) af[mi] = *(const s8v*)(&As[wr * 64 + mi * 16 + r_lo][kc]);
    #pragma unroll
    for (int ni = 0; ni < 4; ++ni) bfr[ni] = *(const s8v*)(&Bs[wc * 64 + ni * 16 + r_lo][kc]);
    #pragma unroll
    for (int mi = 0; mi < 4; ++mi)
      #pragma unroll
      for (int ni = 0; ni < 4; ++ni)
        acc[mi][ni] = __builtin_amdgcn_mfma_f32_16x16x32_bf16(af[mi], bfr[ni], acc[mi][ni], 0, 0, 0);
    __syncthreads();
  }
  // s is constant for the whole wave-row block: m&63 = mi*16 + row_hi + r
  int s = (m0 + wr * 64) >> 6;
  #pragma unroll
  for (int mi = 0; mi < 4; ++mi)
    #pragma unroll
    for (int ni = 0; ni < 4; ++ni) {
      int n2 = n0 + wc * 64 + ni * 16 + r_lo;
      float bias = n2 < 1024 ? bf_[n2] : bb_[n2 - 1024];
      int dir = n2 >> 10, n = n2 & 1023;
      union { u16 u[4]; ll v; } pk4;
      #pragma unroll
      for (int r = 0; r < 4; ++r) pk4.u[r] = f2bf(acc[mi][ni][r] + bias);
      // bg = mi, b&15 = row_hi + r (consecutive) -> one 8-byte store
      *(ll*)(xgt + ((((size_t)dir * 4 + mi) * 256 + s) * 1024 + n) * 16 + row_hi) = pk4.v;
    }
}

// ---------------- K3: LSTM, zero inter-workgroup communication ----------------
// 8 wgs = 2 dir x 4 batch-groups(16), 512 threads = 8 waves = 2 waves/SIMD.
// Wave w owns units [w*32, w*32+32) for all 4 gates: wf = 128 VGPR/lane.
// h fp8 ping-pong in LDS (XOR-swizzled); xg prefetched 1 step ahead into C-in.
__global__ __launch_bounds__(512, 2) void k_lstm(
    const u16* __restrict__ xgt, const u8* __restrict__ whh8,
    u16* __restrict__ hidden) {
  __shared__ u8 hs[2][16 * 256];
  int wg = blockIdx.x, dir = wg >> 2, bg = wg & 3;
  int tid = threadIdx.x, lane = tid & 63, w = tid >> 6;  // w in 0..7
  int r_lo = lane & 15, hi = lane >> 4;

  // nt = g*2 + ut (g=gate 0..3, ut=0..1): N-row = g*256 + w*32 + ut*16 + r_lo
  ll wf[8][8];
  const u8* wb = whh8 + (size_t)dir * 1024 * 256;
  #pragma unroll
  for (int g = 0; g < 4; ++g)
    #pragma unroll
    for (int ut = 0; ut < 2; ++ut) {
      const u8* rp = wb + (size_t)(g * 256 + w * 32 + ut * 16 + r_lo) * 256 + hi * 8;
      #pragma unroll
      for (int kt = 0; kt < 8; ++kt)
        wf[g * 2 + ut][kt] = *(const ll*)(rp + kt * 32);
    }
  for (int i = tid; i < 2 * 16 * 256 / 4; i += 512) ((int*)hs)[i] = 0;
  float c[8];
  #pragma unroll
  for (int i = 0; i < 8; ++i) c[i] = 0.f;

  const u16* xbase = xgt + (((size_t)(dir * 4 + bg) * 256) * 1024 + w * 32) * 16;
  ll xb[8];
  {
    int s0 = dir ? 255 : 0;
    #pragma unroll
    for (int g = 0; g < 4; ++g)
      #pragma unroll
      for (int ut = 0; ut < 2; ++ut)
        xb[g * 2 + ut] = *(const ll*)(xbase + ((size_t)s0 * 1024 + g * 256 + ut * 16 + r_lo) * 16 + hi * 4);
  }
  __syncthreads();

  u16* hidb = hidden + (size_t)(bg * 16) * 512 + dir * 256 + w * 32;
  for (int step = 0; step < 256; ++step) {
    int s = dir ? 255 - step : step;
    // acc starts at xg (bias + input projection already folded in)
    f4v acc[8];
    #pragma unroll
    for (int nt = 0; nt < 8; ++nt) {
      unsigned lo = (unsigned)(unsigned long)xb[nt];
      unsigned h32 = (unsigned)(((unsigned long)xb[nt]) >> 32);
      acc[nt][0] = bf2f((u16)(lo & 0xffff));
      acc[nt][1] = bf2f((u16)(lo >> 16));
      acc[nt][2] = bf2f((u16)(h32 & 0xffff));
      acc[nt][3] = bf2f((u16)(h32 >> 16));
    }
    // prefetch next step's xg (latency hidden under MFMA+epilogue)
    if (step < 255) {
      int sn = dir ? 254 - step : step + 1;
      #pragma unroll
      for (int g = 0; g < 4; ++g)
        #pragma unroll
        for (int ut = 0; ut < 2; ++ut)
          xb[g * 2 + ut] = *(const ll*)(xbase + ((size_t)sn * 1024 + g * 256 + ut * 16 + r_lo) * 16 + hi * 4);
    }
    // A-fragments: h[b=lane&15][k], XOR-swizzled byte chunks
    const u8* hp = hs[step & 1];
    ll av[8];
    #pragma unroll
    for (int kt = 0; kt < 8; ++kt)
      av[kt] = *(const ll*)(hp + r_lo * 256 + ((kt * 32 + hi * 8) ^ (r_lo << 3)));
    #pragma unroll
    for (int kt = 0; kt < 8; ++kt)
      #pragma unroll
      for (int nt = 0; nt < 8; ++nt)
        acc[nt] = __builtin_amdgcn_mfma_f32_16x16x32_fp8_fp8(av[kt], wf[nt][kt], acc[nt], 0, 0, 0);
    // epilogue: lane owns (b = hi*4+q, u = w*32 + ut*16 + r_lo)
    u8* hq = hs[(step + 1) & 1];
    u16* hrow = hidb + (size_t)s * 64 * 512;
    #pragma unroll
    for (int q = 0; q < 4; ++q) {
      int b = hi * 4 + q;
      #pragma unroll
      for (int ut = 0; ut < 2; ++ut) {
        float gi = acc[0 + ut][q], gf = acc[2 + ut][q];
        float gg = acc[4 + ut][q], go = acc[6 + ut][q];
        float cv = sigf(gf) * c[q * 2 + ut] + sigf(gi) * tanhf_(gg);
        c[q * 2 + ut] = cv;
        float hv = sigf(go) * tanhf_(cv);
        hq[b * 256 + ((w * 32 + ut * 16 + r_lo) ^ (b << 3))] = f2fp8(hv);
        hrow[(size_t)b * 512 + ut * 16 + r_lo] = f2bf(hv);
      }
    }
    __syncthreads();
  }
}

// ---------------- K4: emission GEMM ----------------
__global__ __launch_bounds__(64) void k_emit(
    const u16* __restrict__ hidden, const u16* __restrict__ wob,
    const float* __restrict__ bout, float* __restrict__ em) {
  int m0 = blockIdx.x * 16;
  int lane = threadIdx.x;
  int r_lo = lane & 15, kc = (lane >> 4) * 8, row_hi = (lane >> 4) * 4;
  f4v acc[3] = {};
  #pragma unroll
  for (int kt = 0; kt < 16; ++kt) {
    int k0 = kt * 32 + kc;
    s8v a = *(const s8v*)(hidden + (size_t)(m0 + r_lo) * 512 + k0);
    #pragma unroll
    for (int nt = 0; nt < 3; ++nt) {
      s8v b = *(const s8v*)(wob + (size_t)(nt * 16 + r_lo) * 512 + k0);
      acc[nt] = __builtin_amdgcn_mfma_f32_16x16x32_bf16(a, b, acc[nt], 0, 0, 0);
    }
  }
  #pragma unroll
  for (int nt = 0; nt < 3; ++nt) {
    int t = nt * 16 + r_lo;
    if (t < TT) {
      float bo = bout[t];
      #pragma unroll
      for (int r = 0; r < 4; ++r)
        em[(size_t)(m0 + row_hi + r) * 36 + t] = acc[nt][r] + bo;
    }
  }
}

// ---------------- K5: CRF per-sequence NLL ----------------
__global__ __launch_bounds__(64) void k_crf(
    const float* __restrict__ em, const int* __restrict__ tags,
    const float* __restrict__ startt, const float* __restrict__ endt,
    const float* __restrict__ trans, float* __restrict__ llh) {
  __shared__ float tr[34][35];
  __shared__ float al[2][40];
  int b = blockIdx.x, l = threadIdx.x;
  for (int i = l; i < TT * TT; i += 64) tr[i / TT][i - (i / TT) * TT] = trans[i];
  const int* tg = tags + b * SS;
  float np = 0.f;
  for (int s = l; s < SS; s += 64) {
    int t = tg[s];
    np += em[(size_t)(s * 64 + b) * 36 + t];
    if (s < SS - 1) np += trans[t * TT + tg[s + 1]];
  }
  #pragma unroll
  for (int o = 32; o; o >>= 1) np += __shfl_down(np, o, 64);
  float num = 0.f;
  if (l == 0) num = np + startt[tg[0]] + endt[tg[SS - 1]];
  if (l < TT) al[0][l] = startt[l] + em[(size_t)(0 * 64 + b) * 36 + l];
  __syncthreads();
  for (int s = 1; s < SS; ++s) {
    int p = s & 1;
    if (l < TT) {
      float m = -1e30f;
      for (int t = 0; t < TT; ++t) m = fmaxf(m, al[p ^ 1][t] + tr[t][l]);
      float sum = 0.f;
      for (int t = 0; t < TT; ++t) sum += __expf(al[p ^ 1][t] + tr[t][l] - m);
      al[p][l] = m + __logf(sum) + em[(size_t)(s * 64 + b) * 36 + l];
    }
    __syncthreads();
  }
  if (l == 0) {
    int p = (SS - 1) & 1;
    float m = -1e30f;
    for (int t = 0; t < TT; ++t) m = fmaxf(m, al[p][t] + endt[t]);
    float sum = 0.f;
    for (int t = 0; t < TT; ++t) sum += __expf(al[p][t] + endt[t] - m);
    llh[b] = num - (m + __logf(sum));
  }
}

// ---------------- K6: final reduce ----------------
__global__ __launch_bounds__(64) void k_red(const float* __restrict__ llh, float* __restrict__ out) {
  float v = llh[threadIdx.x];
  #pragma unroll
  for (int o = 32; o; o >>= 1) v += __shfl_down(v, o, 64);
  if (threadIdx.x == 0) out[0] = -v * (1.f / 64.f);
}

extern "C" void kernel_launch(void* const* d_in, const int* in_sizes, int n_in,
                              void* d_out, int out_size, void* d_ws, size_t ws_size,
                              hipStream_t stream) {
  const int* batch = (const int*)d_in[0];
  const int* tags = (const int*)d_in[1];
  const float* emb = (const float*)d_in[3];
  const float* wihf = (const float*)d_in[4];
  const float* whhf = (const float*)d_in[5];
  const float* bf_ = (const float*)d_in[6];
  const float* wihb = (const float*)d_in[7];
  const float* whhb = (const float*)d_in[8];
  const float* bb_ = (const float*)d_in[9];
  const float* wout = (const float*)d_in[10];
  const float* bout = (const float*)d_in[11];
  const float* startt = (const float*)d_in[12];
  const float* endt = (const float*)d_in[13];
  const float* trans = (const float*)d_in[14];

  char* ws = (char*)d_ws;
  u16* xbf  = (u16*)(ws + OFF_XBF);
  u16* wih  = (u16*)(ws + OFF_WIH);
  u8*  whh8 = (u8*)(ws + OFF_WHH8);
  u16* wob  = (u16*)(ws + OFF_WOUT);
  u16* xgt  = (u16*)(ws + OFF_XG);
  u16* hid  = (u16*)(ws + OFF_HID);
  float* em = (float*)(ws + OFF_EM);
  float* llh = (float*)(ws + OFF_LLH);
  float* out = (float*)d_out;

  k_prep<<<(TOT_CH + 255) / 256, 256, 0, stream>>>(batch, emb, wihf, wihb, whhf, whhb, wout,
                                                   xbf, wih, whh8, wob);
  k_xg<<<dim3(MM / 128, 2048 / 128), 256, 0, stream>>>(xbf, wih, bf_, bb_, xgt);
  k_lstm<<<8, 512, 0, stream>>>(xgt, whh8, hid);
  k_emit<<<MM / 16, 64, 0, stream>>>(hid, wob, bout, em);
  k_crf<<<64, 64, 0, stream>>>(em, tags, startt, endt, trans, llh);
  k_red<<<1, 64, 0, stream>>>(llh, out);
}

// Round 7
// 1173.699 us; speedup vs baseline: 1.7396x; 1.1700x over previous
//
#include <hip/hip_runtime.h>

typedef short s8v __attribute__((ext_vector_type(8)));
typedef float f4v __attribute__((ext_vector_type(4)));
typedef unsigned short u16;
typedef unsigned char u8;
typedef long ll;  // 64-bit on amdgcn

// ---------------- sizes ----------------
// V=50000 D=300 H=256 T=34 B=64 S=256; M = S*B = 16384; K_in padded 300->320
constexpr int MB = 64, SS = 256, DD = 300, DP = 320, HH = 256, TT = 34, TP = 48;
constexpr int MM = MB * SS;

// workspace offsets (bytes) — total ~98.6 MB
constexpr size_t OFF_XBF  = 0;                                    // [16384][320] bf16
constexpr size_t OFF_WIH  = OFF_XBF  + (size_t)MM * DP * 2;       // [2048][320] bf16
constexpr size_t OFF_WHH8 = OFF_WIH  + (size_t)2048 * DP * 2;     // [2][1024][256] fp8 e4m3
constexpr size_t OFF_WOUT = OFF_WHH8 + (size_t)2048 * HH;         // [48][512] bf16
constexpr size_t OFF_XG   = OFF_WOUT + (size_t)TP * 512 * 2;      // [2dir][4bg][256s][1024n][16b] bf16
constexpr size_t OFF_HID  = OFF_XG   + (size_t)2 * 4 * 256 * 1024 * 16 * 2; // [16384][512] bf16
constexpr size_t OFF_EM   = OFF_HID  + (size_t)MM * 512 * 2;      // [16384][36] f32
constexpr size_t OFF_LLH  = OFF_EM   + (size_t)MM * 36 * 4;      // [64] f32

__device__ inline u16 f2bf(float f) {
  unsigned u = __builtin_bit_cast(unsigned, f);
  unsigned r = u + 0x7fffu + ((u >> 16) & 1u);
  return (u16)(r >> 16);
}
__device__ inline float bf2f(u16 h) {
  return __builtin_bit_cast(float, (unsigned)h << 16);
}
__device__ inline float sigf(float x) { return __fdividef(1.f, 1.f + __expf(-x)); }
__device__ inline float tanhf_(float x) {
  float e = __expf(2.f * x);
  return __fdividef(e - 1.f, e + 1.f);
}
// f32 -> fp8 e4m3 (OCP, RNE + sat via HW convert)
__device__ inline u8 f2fp8(float f) {
  unsigned v;
  asm("v_cvt_pk_fp8_f32 %0, %1, %2" : "=v"(v) : "v"(f), "v"(f));
  return (u8)(v & 0xff);
}
// unpack 4 packed bf16 (2x u32) -> f32x4, 1 inst/value
__device__ inline f4v unpk(unsigned lo, unsigned hi32) {
  f4v r;
  r[0] = __builtin_bit_cast(float, lo << 16);
  r[1] = __builtin_bit_cast(float, lo & 0xffff0000u);
  r[2] = __builtin_bit_cast(float, hi32 << 16);
  r[3] = __builtin_bit_cast(float, hi32 & 0xffff0000u);
  return r;
}

// ---------------- K1: gather + conversions ----------------
constexpr int XBF_CH = MM * (DP / 8);       // 655360
constexpr int WIH_CH = 2048 * (DP / 8);     // 81920
constexpr int WHH_CH = 2048 * (HH / 8);     // 65536 (-> fp8 bytes)
constexpr int WOUT_CH = TP * (512 / 8);     // 3072
constexpr int TOT_CH = XBF_CH + WIH_CH + WHH_CH + WOUT_CH;

__global__ __launch_bounds__(256) void k_prep(
    const int* __restrict__ batch, const float* __restrict__ emb,
    const float* __restrict__ wihf, const float* __restrict__ wihb,
    const float* __restrict__ whhf, const float* __restrict__ whhb,
    const float* __restrict__ wout,
    u16* __restrict__ xbf, u16* __restrict__ wih,
    u8* __restrict__ whh8, u16* __restrict__ wob) {
  int cid = blockIdx.x * 256 + threadIdx.x;
  if (cid >= TOT_CH) return;
  union { u16 u[8]; uint4 v; } pk;
  if (cid < XBF_CH) {
    int m = cid / 40, cc = cid - m * 40, d0 = cc * 8;
    int b = m & 63, s = m >> 6;
    int tok = batch[b * SS + s];
    const float* src = emb + (size_t)tok * DD;
    #pragma unroll
    for (int j = 0; j < 8; ++j) { int d = d0 + j; pk.u[j] = f2bf(d < DD ? src[d] : 0.f); }
    *(uint4*)(xbf + (size_t)m * DP + d0) = pk.v;
  } else if (cid < XBF_CH + WIH_CH) {
    int c2 = cid - XBF_CH;
    int row = c2 / 40, cc = c2 - row * 40, d0 = cc * 8;
    const float* src = row < 1024 ? (wihf + (size_t)row * DD) : (wihb + (size_t)(row - 1024) * DD);
    #pragma unroll
    for (int j = 0; j < 8; ++j) { int d = d0 + j; pk.u[j] = f2bf(d < DD ? src[d] : 0.f); }
    *(uint4*)(wih + (size_t)row * DP + d0) = pk.v;
  } else if (cid < XBF_CH + WIH_CH + WHH_CH) {
    int c2 = cid - (XBF_CH + WIH_CH);
    int row = c2 >> 5, d0 = (c2 & 31) * 8;
    const float* src = (row < 1024 ? whhf + (size_t)row * HH : whhb + (size_t)(row - 1024) * HH) + d0;
    unsigned q0, q1, q2, q3;
    asm("v_cvt_pk_fp8_f32 %0, %1, %2" : "=v"(q0) : "v"(src[0]), "v"(src[1]));
    asm("v_cvt_pk_fp8_f32 %0, %1, %2" : "=v"(q1) : "v"(src[2]), "v"(src[3]));
    asm("v_cvt_pk_fp8_f32 %0, %1, %2" : "=v"(q2) : "v"(src[4]), "v"(src[5]));
    asm("v_cvt_pk_fp8_f32 %0, %1, %2" : "=v"(q3) : "v"(src[6]), "v"(src[7]));
    uint2 o;
    o.x = (q0 & 0xffffu) | (q1 << 16);
    o.y = (q2 & 0xffffu) | (q3 << 16);
    *(uint2*)(whh8 + (size_t)row * HH + d0) = o;
  } else {
    int c2 = cid - (XBF_CH + WIH_CH + WHH_CH);
    int row = c2 >> 6, d0 = (c2 & 63) * 8;
    #pragma unroll
    for (int j = 0; j < 8; ++j) pk.u[j] = f2bf(row < TT ? wout[(size_t)row * 512 + d0 + j] : 0.f);
    *(uint4*)(wob + (size_t)row * 512 + d0) = pk.v;
  }
}

// ---------------- K2: input GEMM: xgt[dir][bg][s][n][b16] = xbf[m][k].wih[n][k] + bias ----------------
__global__ __launch_bounds__(256) void k_xg(
    const u16* __restrict__ xbf, const u16* __restrict__ wih,
    const float* __restrict__ bf_, const float* __restrict__ bb_,
    u16* __restrict__ xgt) {
  __shared__ u16 As[128][40];
  __shared__ u16 Bs[128][40];
  int m0 = blockIdx.x * 128, n0 = blockIdx.y * 128;
  int tid = threadIdx.x, lane = tid & 63, wid = tid >> 6;
  int wr = wid >> 1, wc = wid & 1;
  int r_lo = lane & 15, kc = (lane >> 4) * 8, row_hi = (lane >> 4) * 4;
  f4v acc[4][4] = {};
  for (int kt = 0; kt < 10; ++kt) {
    int k0 = kt * 32;
    #pragma unroll
    for (int i = 0; i < 2; ++i) {
      int cid = tid + 256 * i;
      int row = cid >> 2, cc = cid & 3;
      *(uint4*)(&As[row][cc * 8]) = *(const uint4*)(xbf + (size_t)(m0 + row) * DP + k0 + cc * 8);
      *(uint4*)(&Bs[row][cc * 8]) = *(const uint4*)(wih + (size_t)(n0 + row) * DP + k0 + cc * 8);
    }
    __syncthreads();
    s8v af[4], bfr[4];
    #pragma unroll
    for (int mi = 0; mi < 4; ++mi) af[mi] = *(const s8v*)(&As[wr * 64 + mi * 16 + r_lo][kc]);
    #pragma unroll
    for (int ni = 0; ni < 4; ++ni) bfr[ni] = *(const s8v*)(&Bs[wc * 64 + ni * 16 + r_lo][kc]);
    #pragma unroll
    for (int mi = 0; mi < 4; ++mi)
      #pragma unroll
      for (int ni = 0; ni < 4; ++ni)
        acc[mi][ni] = __builtin_amdgcn_mfma_f32_16x16x32_bf16(af[mi], bfr[ni], acc[mi][ni], 0, 0, 0);
    __syncthreads();
  }
  // s is constant for the whole wave-row block: m&63 = mi*16 + row_hi + r
  int s = (m0 + wr * 64) >> 6;
  #pragma unroll
  for (int mi = 0; mi < 4; ++mi)
    #pragma unroll
    for (int ni = 0; ni < 4; ++ni) {
      int n2 = n0 + wc * 64 + ni * 16 + r_lo;
      float bias = n2 < 1024 ? bf_[n2] : bb_[n2 - 1024];
      int dir = n2 >> 10, n = n2 & 1023;
      union { u16 u[4]; ll v; } pk4;
      #pragma unroll
      for (int r = 0; r < 4; ++r) pk4.u[r] = f2bf(acc[mi][ni][r] + bias);
      // bg = mi, b&15 = row_hi + r (consecutive) -> one 8-byte store
      *(ll*)(xgt + ((((size_t)dir * 4 + mi) * 256 + s) * 1024 + n) * 16 + row_hi) = pk4.v;
    }
}

// ---------------- K3: LSTM, zero inter-workgroup communication ----------------
// 8 wgs = 2 dir x 4 batch-groups(16), 512 threads = 8 waves = 2 waves/SIMD.
// Gate-grouped half-steps: MFMA(ut0) || unpack/prefetch -> MFMA(ut1) ||
// epilogue(ut0) -> epilogue(ut1). LDS-only barrier (lgkmcnt) so the xg
// prefetch + h global stores stay in flight across it.
__global__ __launch_bounds__(512, 2) void k_lstm(
    const u16* __restrict__ xgt, const u8* __restrict__ whh8,
    u16* __restrict__ hidden) {
  __shared__ u8 hs[2][16 * 256];
  int wg = blockIdx.x, dir = wg >> 2, bg = wg & 3;
  int tid = threadIdx.x, lane = tid & 63, w = tid >> 6;  // w in 0..7
  int r_lo = lane & 15, hi = lane >> 4;

  // nt = g*2 + ut (g=gate 0..3, ut=0..1): N-row = g*256 + w*32 + ut*16 + r_lo
  ll wf[8][8];
  const u8* wb = whh8 + (size_t)dir * 1024 * 256;
  #pragma unroll
  for (int g = 0; g < 4; ++g)
    #pragma unroll
    for (int ut = 0; ut < 2; ++ut) {
      const u8* rp = wb + (size_t)(g * 256 + w * 32 + ut * 16 + r_lo) * 256 + hi * 8;
      #pragma unroll
      for (int kt = 0; kt < 8; ++kt)
        wf[g * 2 + ut][kt] = *(const ll*)(rp + kt * 32);
    }
  for (int i = tid; i < 16 * 256 / 4; i += 512) ((int*)hs[0])[i] = 0;
  float c[8];
  #pragma unroll
  for (int i = 0; i < 8; ++i) c[i] = 0.f;

  const u16* xptr = xgt + (((size_t)(dir * 4 + bg) * 256 + (dir ? 255 : 0)) * 1024 + w * 32) * 16;
  const long xstep = dir ? -(1024 * 16) : (1024 * 16);
  unsigned xb[8][2];
  #pragma unroll
  for (int g = 0; g < 4; ++g)
    #pragma unroll
    for (int ut = 0; ut < 2; ++ut) {
      uint2 v = *(const uint2*)(xptr + ((size_t)g * 256 + ut * 16 + r_lo) * 16 + hi * 4);
      xb[g * 2 + ut][0] = v.x; xb[g * 2 + ut][1] = v.y;
    }
  u16* hptr = hidden + ((size_t)(dir ? 255 : 0) * 64 + bg * 16) * 512 + dir * 256 + w * 32;
  const long hstep = dir ? -(64 * 512) : (64 * 512);
  __syncthreads();

  for (int step = 0; step < 256; ++step) {
    // A-fragments: h[b=lane&15][k], XOR-swizzled byte chunks
    const u8* hp = hs[step & 1];
    ll av[8];
    #pragma unroll
    for (int kt = 0; kt < 8; ++kt)
      av[kt] = *(const ll*)(hp + r_lo * 256 + ((kt * 32 + hi * 8) ^ (r_lo << 3)));
    // --- half-step ut=0: gates i,f,g,o for units w*32 + r_lo ---
    f4v a0 = unpk(xb[0][0], xb[0][1]);
    f4v a1 = unpk(xb[2][0], xb[2][1]);
    f4v a2 = unpk(xb[4][0], xb[4][1]);
    f4v a3 = unpk(xb[6][0], xb[6][1]);
    #pragma unroll
    for (int kt = 0; kt < 8; ++kt) {
      a0 = __builtin_amdgcn_mfma_f32_16x16x32_fp8_fp8(av[kt], wf[0][kt], a0, 0, 0, 0);
      a1 = __builtin_amdgcn_mfma_f32_16x16x32_fp8_fp8(av[kt], wf[2][kt], a1, 0, 0, 0);
      a2 = __builtin_amdgcn_mfma_f32_16x16x32_fp8_fp8(av[kt], wf[4][kt], a2, 0, 0, 0);
      a3 = __builtin_amdgcn_mfma_f32_16x16x32_fp8_fp8(av[kt], wf[6][kt], a3, 0, 0, 0);
    }
    // --- half-step ut=1 C-in unpack (overlaps matrix pipe) ---
    f4v b0 = unpk(xb[1][0], xb[1][1]);
    f4v b1 = unpk(xb[3][0], xb[3][1]);
    f4v b2 = unpk(xb[5][0], xb[5][1]);
    f4v b3 = unpk(xb[7][0], xb[7][1]);
    // --- prefetch next step's xg (stays in flight across barrier) ---
    if (step < 255) {
      xptr += xstep;
      #pragma unroll
      for (int g = 0; g < 4; ++g)
        #pragma unroll
        for (int ut = 0; ut < 2; ++ut) {
          uint2 v = *(const uint2*)(xptr + ((size_t)g * 256 + ut * 16 + r_lo) * 16 + hi * 4);
          xb[g * 2 + ut][0] = v.x; xb[g * 2 + ut][1] = v.y;
        }
    }
    #pragma unroll
    for (int kt = 0; kt < 8; ++kt) {
      b0 = __builtin_amdgcn_mfma_f32_16x16x32_fp8_fp8(av[kt], wf[1][kt], b0, 0, 0, 0);
      b1 = __builtin_amdgcn_mfma_f32_16x16x32_fp8_fp8(av[kt], wf[3][kt], b1, 0, 0, 0);
      b2 = __builtin_amdgcn_mfma_f32_16x16x32_fp8_fp8(av[kt], wf[5][kt], b2, 0, 0, 0);
      b3 = __builtin_amdgcn_mfma_f32_16x16x32_fp8_fp8(av[kt], wf[7][kt], b3, 0, 0, 0);
    }
    // --- epilogue ut=0 (VALU/trans overlaps ut=1 MFMA chains) ---
    u8* hq = hs[(step + 1) & 1];
    #pragma unroll
    for (int q = 0; q < 4; ++q) {
      int b = hi * 4 + q;
      float cv = sigf(a1[q]) * c[q * 2] + sigf(a0[q]) * tanhf_(a2[q]);
      c[q * 2] = cv;
      float hv = sigf(a3[q]) * tanhf_(cv);
      hq[b * 256 + ((w * 32 + r_lo) ^ (b << 3))] = f2fp8(hv);
      hptr[(size_t)b * 512 + r_lo] = f2bf(hv);
    }
    // --- epilogue ut=1 ---
    #pragma unroll
    for (int q = 0; q < 4; ++q) {
      int b = hi * 4 + q;
      float cv = sigf(b1[q]) * c[q * 2 + 1] + sigf(b0[q]) * tanhf_(b2[q]);
      c[q * 2 + 1] = cv;
      float hv = sigf(b3[q]) * tanhf_(cv);
      hq[b * 256 + ((w * 32 + 16 + r_lo) ^ (b << 3))] = f2fp8(hv);
      hptr[(size_t)b * 512 + 16 + r_lo] = f2bf(hv);
    }
    hptr += hstep;
    // LDS-only drain + barrier: global loads/stores stay in flight.
    asm volatile("s_waitcnt lgkmcnt(0)\n\ts_barrier" ::: "memory");
  }
}

// ---------------- K4: emission GEMM ----------------
__global__ __launch_bounds__(64) void k_emit(
    const u16* __restrict__ hidden, const u16* __restrict__ wob,
    const float* __restrict__ bout, float* __restrict__ em) {
  int m0 = blockIdx.x * 16;
  int lane = threadIdx.x;
  int r_lo = lane & 15, kc = (lane >> 4) * 8, row_hi = (lane >> 4) * 4;
  f4v acc[3] = {};
  #pragma unroll
  for (int kt = 0; kt < 16; ++kt) {
    int k0 = kt * 32 + kc;
    s8v a = *(const s8v*)(hidden + (size_t)(m0 + r_lo) * 512 + k0);
    #pragma unroll
    for (int nt = 0; nt < 3; ++nt) {
      s8v b = *(const s8v*)(wob + (size_t)(nt * 16 + r_lo) * 512 + k0);
      acc[nt] = __builtin_amdgcn_mfma_f32_16x16x32_bf16(a, b, acc[nt], 0, 0, 0);
    }
  }
  #pragma unroll
  for (int nt = 0; nt < 3; ++nt) {
    int t = nt * 16 + r_lo;
    if (t < TT) {
      float bo = bout[t];
      #pragma unroll
      for (int r = 0; r < 4; ++r)
        em[(size_t)(m0 + row_hi + r) * 36 + t] = acc[nt][r] + bo;
    }
  }
}

// ---------------- K5: CRF per-sequence NLL ----------------
__global__ __launch_bounds__(64) void k_crf(
    const float* __restrict__ em, const int* __restrict__ tags,
    const float* __restrict__ startt, const float* __restrict__ endt,
    const float* __restrict__ trans, float* __restrict__ llh) {
  __shared__ float tr[34][35];
  __shared__ float al[2][40];
  int b = blockIdx.x, l = threadIdx.x;
  for (int i = l; i < TT * TT; i += 64) tr[i / TT][i - (i / TT) * TT] = trans[i];
  const int* tg = tags + b * SS;
  float np = 0.f;
  for (int s = l; s < SS; s += 64) {
    int t = tg[s];
    np += em[(size_t)(s * 64 + b) * 36 + t];
    if (s < SS - 1) np += trans[t * TT + tg[s + 1]];
  }
  #pragma unroll
  for (int o = 32; o; o >>= 1) np += __shfl_down(np, o, 64);
  float num = 0.f;
  if (l == 0) num = np + startt[tg[0]] + endt[tg[SS - 1]];
  if (l < TT) al[0][l] = startt[l] + em[(size_t)(0 * 64 + b) * 36 + l];
  __syncthreads();
  for (int s = 1; s < SS; ++s) {
    int p = s & 1;
    if (l < TT) {
      // 2-way independent partials to halve the dependent-chain latency
      float m0 = -1e30f, m1 = -1e30f;
      #pragma unroll
      for (int t = 0; t < TT; t += 2) {
        m0 = fmaxf(m0, al[p ^ 1][t] + tr[t][l]);
        m1 = fmaxf(m1, al[p ^ 1][t + 1] + tr[t + 1][l]);
      }
      float m = fmaxf(m0, m1);
      float s0 = 0.f, s1 = 0.f;
      #pragma unroll
      for (int t = 0; t < TT; t += 2) {
        s0 += __expf(al[p ^ 1][t] + tr[t][l] - m);
        s1 += __expf(al[p ^ 1][t + 1] + tr[t + 1][l] - m);
      }
      al[p][l] = m + __logf(s0 + s1) + em[(size_t)(s * 64 + b) * 36 + l];
    }
    __syncthreads();
  }
  if (l == 0) {
    int p = (SS - 1) & 1;
    float m = -1e30f;
    for (int t = 0; t < TT; ++t) m = fmaxf(m, al[p][t] + endt[t]);
    float sum = 0.f;
    for (int t = 0; t < TT; ++t) sum += __expf(al[p][t] + endt[t] - m);
    llh[b] = num - (m + __logf(sum));
  }
}

// ---------------- K6: final reduce ----------------
__global__ __launch_bounds__(64) void k_red(const float* __restrict__ llh, float* __restrict__ out) {
  float v = llh[threadIdx.x];
  #pragma unroll
  for (int o = 32; o; o >>= 1) v += __shfl_down(v, o, 64);
  if (threadIdx.x == 0) out[0] = -v * (1.f / 64.f);
}

extern "C" void kernel_launch(void* const* d_in, const int* in_sizes, int n_in,
                              void* d_out, int out_size, void* d_ws, size_t ws_size,
                              hipStream_t stream) {
  const int* batch = (const int*)d_in[0];
  const int* tags = (const int*)d_in[1];
  const float* emb = (const float*)d_in[3];
  const float* wihf = (const float*)d_in[4];
  const float* whhf = (const float*)d_in[5];
  const float* bf_ = (const float*)d_in[6];
  const float* wihb = (const float*)d_in[7];
  const float* whhb = (const float*)d_in[8];
  const float* bb_ = (const float*)d_in[9];
  const float* wout = (const float*)d_in[10];
  const float* bout = (const float*)d_in[11];
  const float* startt = (const float*)d_in[12];
  const float* endt = (const float*)d_in[13];
  const float* trans = (const float*)d_in[14];

  char* ws = (char*)d_ws;
  u16* xbf  = (u16*)(ws + OFF_XBF);
  u16* wih  = (u16*)(ws + OFF_WIH);
  u8*  whh8 = (u8*)(ws + OFF_WHH8);
  u16* wob  = (u16*)(ws + OFF_WOUT);
  u16* xgt  = (u16*)(ws + OFF_XG);
  u16* hid  = (u16*)(ws + OFF_HID);
  float* em = (float*)(ws + OFF_EM);
  float* llh = (float*)(ws + OFF_LLH);
  float* out = (float*)d_out;

  k_prep<<<(TOT_CH + 255) / 256, 256, 0, stream>>>(batch, emb, wihf, wihb, whhf, whhb, wout,
                                                   xbf, wih, whh8, wob);
  k_xg<<<dim3(MM / 128, 2048 / 128), 256, 0, stream>>>(xbf, wih, bf_, bb_, xgt);
  k_lstm<<<8, 512, 0, stream>>>(xgt, whh8, hid);
  k_emit<<<MM / 16, 64, 0, stream>>>(hid, wob, bout, em);
  k_crf<<<64, 64, 0, stream>>>(em, tags, startt, endt, trans, llh);
  k_red<<<1, 64, 0, stream>>>(llh, out);
}